// Round 7
// baseline (2130.096 us; speedup 1.0000x reference)
//
#include <hip/hip_runtime.h>

// TrajectoryDecoder r7: r6 + (1) gate constants folded into prescaled weights
// (sigmoid/tanh = rcp(1+exp2(fma chain)), biases preloaded into MFMA accs),
// (2) delta = h@W_out via wave-0 MFMA in the NEXT step's K-loop (removes DPP
// reduction + dpart + phase C; r5's bug was a misaligned f32x4 LDS read --
// all pos accesses here are scalar), (3) h carried packed-bf16 in registers
// (r4-verified). Partition unchanged from r6 (PASSED): NSEQ=32, 8 waves,
// wR/wZ register-stationary, wN in LDS, grid 1536, 2 lgkm-only barriers.

typedef __attribute__((ext_vector_type(8))) short short8;
typedef __bf16 bf16x8 __attribute__((ext_vector_type(8)));
typedef float f32x16 __attribute__((ext_vector_type(16)));
typedef float f32x4 __attribute__((ext_vector_type(4)));

#define HSTR 264               // Hb stride: 528B rows, 16B-aligned, uniform banks for b128
#define NSEQ_BLK 32
#define WHH3_ELEMS (24 * 16 * 64 * 8)  // 196608 = 768x256
#define WH0_ELEMS (8 * 20 * 64 * 8)    // 81920
#define WOP_ELEMS (16 * 64 * 8)        // 8192

#define SCL_RZ (-1.4426950408889634f)  // -1/ln2 : sigmoid prescale
#define SCL_N  (2.8853900817779268f)   // +2/ln2 : tanh prescale

static __device__ __forceinline__ unsigned short f2bf(float f) {
  unsigned u = __builtin_bit_cast(unsigned, f);
  u += 0x7fffu + ((u >> 16) & 1u);   // RNE
  return (unsigned short)(u >> 16);
}
static __device__ __forceinline__ float bf2f(unsigned short h) {
  unsigned u = ((unsigned)h) << 16;
  return __builtin_bit_cast(float, u);
}
static __device__ __forceinline__ bf16x8 ldfrag(const unsigned short* p) {
  return __builtin_bit_cast(bf16x8, *(const short8*)p);
}
// LDS-only barrier (r4/r6-verified): no vmcnt drain.
static __device__ __forceinline__ void bar_lgkm() {
  asm volatile("s_waitcnt lgkmcnt(0)\n\ts_barrier" ::: "memory");
}

// ---- prep: pack W_hh slice-major with gate prescale folded in ----
__global__ void prep_whh3_k(const float* __restrict__ Whh, unsigned short* __restrict__ Whhp3) {
  int i = blockIdx.x * 256 + threadIdx.x;
  if (i >= WHH3_ELEMS) return;
  int j = i & 7;
  int lane = (i >> 3) & 63;
  int rest = i >> 9;
  int ks = rest & 15;
  int sw = rest >> 4;
  int g = sw >> 3, w = sw & 7;
  int row = g * 256 + w * 32 + (lane & 31);
  int k = ks * 16 + ((lane >> 5) << 3) + j;
  float scl = (g == 2) ? SCL_N : SCL_RZ;
  Whhp3[i] = f2bf(scl * Whh[row * 256 + k]);
}

// ---- prep: W_out as B-frag stream (unscaled): [ks][lane][8]; col<2 else 0 ----
__global__ void prep_wop_k(const float* __restrict__ Wout, unsigned short* __restrict__ Wop) {
  int i = blockIdx.x * 256 + threadIdx.x;
  if (i >= WOP_ELEMS) return;
  int j = i & 7;
  int lane = (i >> 3) & 63;
  int ks = i >> 9;
  int c = lane & 31;
  int k = ks * 16 + ((lane >> 5) << 3) + j;
  float v = (c < 2) ? Wout[c * 256 + k] : 0.f;
  Wop[i] = f2bf(v);
}

// ---- prep: pack W_h0 (256 x 290, K padded to 320), unscaled (r6-verified) ----
__global__ void prep_wh0_k(const float* __restrict__ Wh0, unsigned short* __restrict__ Wh0p) {
  int i = blockIdx.x * 256 + threadIdx.x;
  if (i >= WH0_ELEMS) return;
  int j = i & 7;
  int lane = (i >> 3) & 63;
  int rest = i >> 9;
  int ks = rest % 20;
  int nt = rest / 20;
  int row = nt * 32 + (lane & 31);
  int k = ks * 16 + ((lane >> 5) << 3) + j;
  float v = (k < 290) ? Wh0[row * 290 + k] : 0.f;
  Wh0p[i] = f2bf(v);
}

// ---- prep: per-h-unit params, PRESCALED:
// [brr', bzz', bin', bhn'(unused slot kept), wr0', wr1', wz0', wz1', wn0', wn1', -, -]
// brr' = SCL_RZ*(bih_r+bhh_r); bin' = SCL_N*bih_n; bhn folded here into slot3 as
// SCL_N*bhh_n which is added to the n-acc init.
__global__ void prep_gp_k(const float* __restrict__ bih, const float* __restrict__ bhh,
                          const float* __restrict__ Wih, const float* __restrict__ Wout,
                          float* __restrict__ gpo) {
  int n = threadIdx.x;
  gpo[n * 12 + 0]  = SCL_RZ * (bih[n] + bhh[n]);
  gpo[n * 12 + 1]  = SCL_RZ * (bih[n + 256] + bhh[n + 256]);
  gpo[n * 12 + 2]  = SCL_N * bih[n + 512];
  gpo[n * 12 + 3]  = SCL_N * bhh[n + 512];
  gpo[n * 12 + 4]  = SCL_RZ * Wih[n * 2 + 0];
  gpo[n * 12 + 5]  = SCL_RZ * Wih[n * 2 + 1];
  gpo[n * 12 + 6]  = SCL_RZ * Wih[(n + 256) * 2 + 0];
  gpo[n * 12 + 7]  = SCL_RZ * Wih[(n + 256) * 2 + 1];
  gpo[n * 12 + 8]  = SCL_N * Wih[(n + 512) * 2 + 0];
  gpo[n * 12 + 9]  = SCL_N * Wih[(n + 512) * 2 + 1];
  gpo[n * 12 + 10] = 0.f;
  gpo[n * 12 + 11] = 0.f;
}

// ---------------- main fused GRU ----------------
__global__ __launch_bounds__(512, 2) void gru_main_k(
    const float* __restrict__ ctx, const float* __restrict__ goals,
    const float* __restrict__ emb, const float* __restrict__ bh0,
    const float* __restrict__ bout,
    const unsigned short* __restrict__ Wh0p,
    const unsigned short* __restrict__ Whhp3,
    const unsigned short* __restrict__ Wop,
    const float* __restrict__ gp,
    float* __restrict__ out) {
  __shared__ __align__(16) unsigned short wNl[8 * 16 * 64 * 8];  // 131072 B
  __shared__ __align__(16) unsigned short Hb[NSEQ_BLK * HSTR];   // 16896 B
  __shared__ __align__(16) float posL[NSEQ_BLK * 2];             // 256 B
  // total 148224 B; 1 block/CU, 8 waves (2/SIMD)

  const int tid = threadIdx.x;
  const int w = tid >> 6;
  const int l = tid & 63;
  const int l31 = l & 31;
  const int grp = l >> 5;
  const int seq0 = blockIdx.x * NSEQ_BLK;
  const int n0 = w * 32 + l31;

  // ---- stage wN (g=2 region, 128 KB) into LDS, block-cooperative ----
  {
    const short8* wsrc = (const short8*)(Whhp3 + 131072);
    short8* wdst = (short8*)wNl;
    for (int i = tid; i < 8192; i += 512) wdst[i] = wsrc[i];
  }
  // ---- preload wR, wZ into registers (128 regs, held 30 steps) ----
  bf16x8 wR[16], wZ[16];
#pragma unroll
  for (int ks = 0; ks < 16; ++ks) {
    wR[ks] = ldfrag(&Whhp3[(((0 * 8 + w) * 16 + ks) * 64 + l) * 8]);
    wZ[ks] = ldfrag(&Whhp3[(((1 * 8 + w) * 16 + ks) * 64 + l) * 8]);
  }

  // ---------------- Phase 0: h0 = init_in @ W_h0^T + b_h0 ----------------
  f32x16 acc0 = f32x16{};
  unsigned short* As = Hb;   // overlay staging, stride 176
  for (int cc = 0; cc < 2; ++cc) {
    for (int i = tid; i < NSEQ_BLK * 160; i += 512) {
      int row = i / 160;
      int col = i - row * 160;
      int d = cc * 160 + col;
      int s = seq0 + row;
      int b = s / 6;
      float v;
      if (d < 256)      v = ctx[b * 256 + d];
      else if (d < 258) v = goals[s * 2 + (d - 256)];
      else if (d < 290) v = emb[b * 32 + (d - 258)];
      else              v = 0.f;
      As[row * 176 + col] = f2bf(v);
    }
    __syncthreads();   // also orders wNl staging (cc=0)
    for (int ks = 0; ks < 10; ++ks) {
      bf16x8 bf = ldfrag(&Wh0p[((w * 20 + cc * 10 + ks) * 64 + l) * 8]);
      bf16x8 af = ldfrag(&As[l31 * 176 + ks * 16 + grp * 8]);
      acc0 = __builtin_amdgcn_mfma_f32_32x32x16_bf16(af, bf, acc0, 0, 0, 0);
    }
    __syncthreads();
  }
  // h0 -> Hb (bf16) + packed-bf16 register copy (r4-verified pattern)
  unsigned hpk[8];
  {
    float b0 = bh0[n0];
    unsigned tmp = 0;
#pragma unroll
    for (int r = 0; r < 16; ++r) {
      int row = (r & 3) + 8 * (r >> 2) + 4 * grp;   // C/D layout [m74/m101]
      unsigned short hb = f2bf(acc0[r] + b0);
      Hb[row * HSTR + n0] = hb;
      if ((r & 1) == 0) tmp = hb;
      else hpk[r >> 1] = tmp | ((unsigned)hb << 16);
    }
  }
  if (tid < 2 * NSEQ_BLK) posL[tid] = 0.f;

  float brr, bzz, bin_, bhn, wr0, wr1, wz0, wz1, wn0, wn1;
  {
    f32x4 g0 = *(const f32x4*)&gp[n0 * 12];
    f32x4 g1 = *(const f32x4*)&gp[n0 * 12 + 4];
    brr = g0[0]; bzz = g0[1]; bin_ = g0[2]; bhn = g0[3];
    wr0 = g1[0]; wr1 = g1[1]; wz0 = g1[2]; wz1 = g1[3];
    wn0 = gp[n0 * 12 + 8]; wn1 = gp[n0 * 12 + 9];
  }
  const float boc = (l31 == 1) ? bout[1] : bout[0];   // per-lane output bias
  __syncthreads();

  // ---------------- T recurrent steps (no weight traffic) ----------------
  for (int t = 0; t < 30; ++t) {
    // acc init = prescaled biases (deletes the adds in phase B)
    f32x16 ar, az, an, aD;
#pragma unroll
    for (int r = 0; r < 16; ++r) { ar[r] = brr; az[r] = bzz; an[r] = bhn; aD[r] = boc; }

    // K-loop: A from Hb, wR/wZ regs, wN LDS; wave 0 also: delta MFMA vs W_out
#pragma unroll
    for (int ks = 0; ks < 16; ++ks) {
      bf16x8 af = ldfrag(&Hb[l31 * HSTR + ks * 16 + grp * 8]);
      bf16x8 bN = ldfrag(&wNl[((w * 16 + ks) * 64 + l) * 8]);
      ar = __builtin_amdgcn_mfma_f32_32x32x16_bf16(af, wR[ks], ar, 0, 0, 0);
      az = __builtin_amdgcn_mfma_f32_32x32x16_bf16(af, wZ[ks], az, 0, 0, 0);
      an = __builtin_amdgcn_mfma_f32_32x32x16_bf16(af, bN, an, 0, 0, 0);
      if (w == 0) {
        bf16x8 woF = ldfrag(&Wop[(ks * 64 + l) * 8]);   // global, L1-hot
        aD = __builtin_amdgcn_mfma_f32_32x32x16_bf16(af, woF, aD, 0, 0, 0);
      }
    }
    // wave 0: pos_{t-1} = pos_{t-2} + h_t@Wout + bo ; store pred[t-1]
    if (t >= 1 && w == 0 && l31 < 2) {
      const int c = l31;
#pragma unroll
      for (int r = 0; r < 16; ++r) {
        int s = (r & 3) + 8 * (r >> 2) + 4 * grp;
        float np = posL[s * 2 + c] + aD[r];             // boc folded in init
        posL[s * 2 + c] = np;
        out[((seq0 + s) * 30 + (t - 1)) * 2 + c] = np;
      }
    }
    bar_lgkm();   // barrier1: Hb reads done; posL = pos_{t-1} visible

    // Phase B: gates (prescaled: pure fma+exp2+rcp) + h update
#pragma unroll
    for (int q2 = 0; q2 < 4; ++q2) {
      int sb = 8 * q2 + 4 * grp;
      f32x4 xyA = *(const f32x4*)&posL[sb * 2];         // 16B-aligned (sb%4==0)
      f32x4 xyB = *(const f32x4*)&posL[sb * 2 + 4];
#pragma unroll
      for (int e = 0; e < 4; ++e) {
        int r = 4 * q2 + e;
        int s = sb + e;
        float x = (e == 0) ? xyA[0] : (e == 1) ? xyA[2] : (e == 2) ? xyB[0] : xyB[2];
        float y = (e == 0) ? xyA[1] : (e == 1) ? xyA[3] : (e == 2) ? xyB[1] : xyB[3];
        unsigned hp = hpk[r >> 1];
        float h = bf2f((unsigned short)((r & 1) ? (hp >> 16) : (hp & 0xffffu)));
        float vr = fmaf(y, wr1, fmaf(x, wr0, ar[r]));
        float rg = __builtin_amdgcn_rcpf(1.f + __builtin_amdgcn_exp2f(vr));
        float vz = fmaf(y, wz1, fmaf(x, wz0, az[r]));
        float zg = __builtin_amdgcn_rcpf(1.f + __builtin_amdgcn_exp2f(vz));
        float ing = fmaf(y, wn1, fmaf(x, wn0, bin_));
        float u = fmaf(rg, an[r], ing);
        float tt = __builtin_amdgcn_rcpf(1.f + __builtin_amdgcn_exp2f(u));
        float ng = fmaf(tt, -2.f, 1.f);                 // tanh
        float hnew = fmaf(zg, h - ng, ng);              // (1-z)*n + z*h
        unsigned short nb = f2bf(hnew);
        hpk[r >> 1] = (r & 1) ? ((hp & 0xffffu) | ((unsigned)nb << 16))
                              : ((hp & 0xffff0000u) | nb);
        Hb[s * HSTR + n0] = nb;
      }
    }
    bar_lgkm();   // barrier2: h_{t+1} visible for next K-loop
  }

  // ---- epilogue: pred[29] = pos_28 + h_30@Wout + bo (wave 0) ----
  if (w == 0) {
    f32x16 aD;
#pragma unroll
    for (int r = 0; r < 16; ++r) aD[r] = boc;
#pragma unroll
    for (int ks = 0; ks < 16; ++ks) {
      bf16x8 woF = ldfrag(&Wop[(ks * 64 + l) * 8]);
      bf16x8 af = ldfrag(&Hb[l31 * HSTR + ks * 16 + grp * 8]);
      aD = __builtin_amdgcn_mfma_f32_32x32x16_bf16(af, woF, aD, 0, 0, 0);
    }
    if (l31 < 2) {
      const int c = l31;
#pragma unroll
      for (int r = 0; r < 16; ++r) {
        int s = (r & 3) + 8 * (r >> 2) + 4 * grp;
        out[((seq0 + s) * 30 + 29) * 2 + c] = posL[s * 2 + c] + aD[r];
      }
    }
  }
}

// ---- correction: out = pred + (goal - pred_T) * (t+1)/30, in place (verified) ----
__global__ void corr_k(float* __restrict__ out, const float* __restrict__ goals) {
  __shared__ float buf[240];
  int tid = threadIdx.x;
  int s0 = blockIdx.x * 4;
  float v = 0.f;
  if (tid < 240) { v = out[s0 * 60 + tid]; buf[tid] = v; }
  __syncthreads();
  if (tid < 240) {
    int sl = tid / 60;
    int rem = tid - sl * 60;
    int t = rem >> 1, c = rem & 1;
    float pT = buf[sl * 60 + 58 + c];
    float g = goals[(s0 + sl) * 2 + c];
    out[s0 * 60 + tid] = v + (g - pT) * ((float)(t + 1) * (1.f / 30.f));
  }
}

extern "C" void kernel_launch(void* const* d_in, const int* in_sizes, int n_in,
                              void* d_out, int out_size, void* d_ws, size_t ws_size,
                              hipStream_t stream) {
  (void)in_sizes; (void)n_in; (void)out_size; (void)ws_size;
  const float* ctx  = (const float*)d_in[0];
  const float* goals= (const float*)d_in[1];
  const float* emb  = (const float*)d_in[2];
  const float* Wh0  = (const float*)d_in[3];
  const float* bh0  = (const float*)d_in[4];
  const float* Wih  = (const float*)d_in[5];
  const float* Whh  = (const float*)d_in[6];
  const float* bih  = (const float*)d_in[7];
  const float* bhh  = (const float*)d_in[8];
  const float* Wout = (const float*)d_in[9];
  const float* bout = (const float*)d_in[10];
  float* out = (float*)d_out;

  unsigned short* Whhp3 = (unsigned short*)d_ws;                       // 393216 B
  unsigned short* Wh0p  = (unsigned short*)((char*)d_ws + 393216);     // 163840 B
  float* gpo = (float*)((char*)d_ws + 393216 + 163840);                // 12288 B
  unsigned short* Wop = (unsigned short*)((char*)d_ws + 393216 + 163840 + 12288); // 16384 B

  hipLaunchKernelGGL(prep_whh3_k, dim3(768), dim3(256), 0, stream, Whh, Whhp3);
  hipLaunchKernelGGL(prep_wh0_k, dim3(320), dim3(256), 0, stream, Wh0, Wh0p);
  hipLaunchKernelGGL(prep_gp_k, dim3(1), dim3(256), 0, stream, bih, bhh, Wih, Wout, gpo);
  hipLaunchKernelGGL(prep_wop_k, dim3(32), dim3(256), 0, stream, Wout, Wop);
  hipLaunchKernelGGL(gru_main_k, dim3(1536), dim3(512), 0, stream,
                     ctx, goals, emb, bh0, bout, Wh0p, Whhp3, Wop, gpo, out);
  hipLaunchKernelGGL(corr_k, dim3(12288), dim3(256), 0, stream, out, goals);
}

// Round 8
// 1253.273 us; speedup vs baseline: 1.6996x; 1.6996x over previous
//
#include <hip/hip_runtime.h>

// TrajectoryDecoder r8: r6 (990us, spill-free, PASSED) + register-neutral
// phase-B cuts: (1) xy folded into r/z MFMAs as K-columns 256-257 (r1-verified
// layout, K=272, 17th weight frag holds prescaled W_ih), (2) weights/biases
// prescaled by -1/ln2 (r/z) and +2/ln2 (n) so sigmoid/tanh = rcp(1+exp2(acc)),
// biases preloaded into MFMA accumulators. Delta stays on the r6-verified DPP
// path. 3 lgkm barriers (r1-verified schedule: C's Hb-xy writes ordered before
// next K-loop). Register delta vs r6: +8 weight frags, -4 scalars = +4.

typedef __attribute__((ext_vector_type(8))) short short8;
typedef __bf16 bf16x8 __attribute__((ext_vector_type(8)));
typedef float f32x16 __attribute__((ext_vector_type(16)));
typedef float f32x4 __attribute__((ext_vector_type(4)));

#define HSTR 280               // Hb stride: cols 0-255 h, 256-257 xy, 258-271 zero, 272-279 pad
#define NSEQ_BLK 32
#define WHH3_ELEMS (24 * 17 * 64 * 8)  // 208896: 3 gates x 8 waves x 17 ks
#define WH0_ELEMS (8 * 20 * 64 * 8)    // 81920

#define SCL_RZ (-1.4426950408889634f)  // -1/ln2 : sigmoid prescale
#define SCL_N  (2.8853900817779268f)   // +2/ln2 : tanh prescale

static __device__ __forceinline__ unsigned short f2bf(float f) {
  unsigned u = __builtin_bit_cast(unsigned, f);
  u += 0x7fffu + ((u >> 16) & 1u);   // RNE
  return (unsigned short)(u >> 16);
}
static __device__ __forceinline__ float bf2f(unsigned short h) {
  unsigned u = ((unsigned)h) << 16;
  return __builtin_bit_cast(float, u);
}
static __device__ __forceinline__ bf16x8 ldfrag(const unsigned short* p) {
  return __builtin_bit_cast(bf16x8, *(const short8*)p);
}
static __device__ __forceinline__ float dpp16sum(float x) {
  x += __builtin_bit_cast(float, __builtin_amdgcn_update_dpp(0, __builtin_bit_cast(int, x), 0xB1, 0xF, 0xF, true));
  x += __builtin_bit_cast(float, __builtin_amdgcn_update_dpp(0, __builtin_bit_cast(int, x), 0x4E, 0xF, 0xF, true));
  x += __builtin_bit_cast(float, __builtin_amdgcn_update_dpp(0, __builtin_bit_cast(int, x), 0x141, 0xF, 0xF, true));
  x += __builtin_bit_cast(float, __builtin_amdgcn_update_dpp(0, __builtin_bit_cast(int, x), 0x140, 0xF, 0xF, true));
  return x;
}
// LDS-only barrier (r4/r6-verified): no vmcnt drain.
static __device__ __forceinline__ void bar_lgkm() {
  asm volatile("s_waitcnt lgkmcnt(0)\n\ts_barrier" ::: "memory");
}

// ---- prep: pack W_hh slice-major, 17 ks, prescaled; ks=16 holds W_ih (r/z) ----
// idx = ((g*8+w)*17 + ks)*512 + lane*8 + j ; row = g*256+w*32+(lane&31),
// k = ks*16 + (lane>>5)*8 + j.  k<256: scl*Whh ; k in {256,257} & g<2: SCL_RZ*Wih ; else 0.
__global__ void prep_whh3_k(const float* __restrict__ Whh, const float* __restrict__ Wih,
                            unsigned short* __restrict__ Whhp3) {
  int i = blockIdx.x * 256 + threadIdx.x;
  if (i >= WHH3_ELEMS) return;
  int j = i & 7;
  int lane = (i >> 3) & 63;
  int rest = i >> 9;
  int ks = rest % 17;
  int sw = rest / 17;
  int g = sw >> 3, w = sw & 7;
  int row = g * 256 + w * 32 + (lane & 31);
  int k = ks * 16 + ((lane >> 5) << 3) + j;
  float v = 0.f;
  if (k < 256)                      v = ((g == 2) ? SCL_N : SCL_RZ) * Whh[row * 256 + k];
  else if (k < 258 && g < 2)        v = SCL_RZ * Wih[row * 2 + (k - 256)];
  Whhp3[i] = f2bf(v);
}

// ---- prep: pack W_h0 (256 x 290, K padded to 320), unscaled (r6-verified) ----
__global__ void prep_wh0_k(const float* __restrict__ Wh0, unsigned short* __restrict__ Wh0p) {
  int i = blockIdx.x * 256 + threadIdx.x;
  if (i >= WH0_ELEMS) return;
  int j = i & 7;
  int lane = (i >> 3) & 63;
  int rest = i >> 9;
  int ks = rest % 20;
  int nt = rest / 20;
  int row = nt * 32 + (lane & 31);
  int k = ks * 16 + ((lane >> 5) << 3) + j;
  float v = (k < 290) ? Wh0[row * 290 + k] : 0.f;
  Wh0p[i] = f2bf(v);
}

// ---- prep: per-h-unit params, prescaled:
// [brr', bzz', bin', bhn', -,-,-,-, wn0', wn1', wo0, wo1] ----
__global__ void prep_gp_k(const float* __restrict__ bih, const float* __restrict__ bhh,
                          const float* __restrict__ Wih, const float* __restrict__ Wout,
                          float* __restrict__ gpo) {
  int n = threadIdx.x;
  gpo[n * 12 + 0]  = SCL_RZ * (bih[n] + bhh[n]);
  gpo[n * 12 + 1]  = SCL_RZ * (bih[n + 256] + bhh[n + 256]);
  gpo[n * 12 + 2]  = SCL_N * bih[n + 512];
  gpo[n * 12 + 3]  = SCL_N * bhh[n + 512];
  gpo[n * 12 + 4]  = 0.f;
  gpo[n * 12 + 5]  = 0.f;
  gpo[n * 12 + 6]  = 0.f;
  gpo[n * 12 + 7]  = 0.f;
  gpo[n * 12 + 8]  = SCL_N * Wih[(n + 512) * 2 + 0];
  gpo[n * 12 + 9]  = SCL_N * Wih[(n + 512) * 2 + 1];
  gpo[n * 12 + 10] = Wout[n];
  gpo[n * 12 + 11] = Wout[256 + n];
}

// ---------------- main fused GRU ----------------
__global__ __launch_bounds__(512, 2) void gru_main_k(
    const float* __restrict__ ctx, const float* __restrict__ goals,
    const float* __restrict__ emb, const float* __restrict__ bh0,
    const float* __restrict__ bout,
    const unsigned short* __restrict__ Wh0p,
    const unsigned short* __restrict__ Whhp3,
    const float* __restrict__ gp,
    float* __restrict__ out) {
  __shared__ __align__(16) unsigned short wNl[8 * 16 * 64 * 8];  // 131072 B (n-gate, ks 0..15)
  __shared__ __align__(16) unsigned short Hb[NSEQ_BLK * HSTR];   // 17920 B
  __shared__ __align__(16) float dpart[16 * NSEQ_BLK * 2];       // 4096 B
  __shared__ __align__(16) float posL[NSEQ_BLK * 2];             // 256 B
  // total 153344 B <= 160 KiB; 1 block/CU, 8 waves (2/SIMD)

  const int tid = threadIdx.x;
  const int w = tid >> 6;
  const int l = tid & 63;
  const int l31 = l & 31;
  const int grp = l >> 5;
  const int seq0 = blockIdx.x * NSEQ_BLK;
  const int n0 = w * 32 + l31;

  // ---- stage wN (g=2, ks 0..15) into LDS, block-cooperative ----
  {
    short8* wdst = (short8*)wNl;
    const short8* wsrc = (const short8*)Whhp3;
    for (int i = tid; i < 8192; i += 512) {
      int wv = i >> 10;
      int rem = i & 1023;
      int ks = rem >> 6;
      int u = rem & 63;
      wdst[i] = wsrc[((16 + wv) * 17 + ks) * 64 + u];
    }
  }
  // ---- preload wR, wZ (17 frags each; ks=16 = prescaled W_ih columns) ----
  bf16x8 wR[17], wZ[17];
#pragma unroll
  for (int ks = 0; ks < 17; ++ks) {
    wR[ks] = ldfrag(&Whhp3[(((0 * 8 + w) * 17 + ks) * 64 + l) * 8]);
    wZ[ks] = ldfrag(&Whhp3[(((1 * 8 + w) * 17 + ks) * 64 + l) * 8]);
  }

  // ---------------- Phase 0: h0 = init_in @ W_h0^T + b_h0 ----------------
  f32x16 acc0 = f32x16{};
  unsigned short* As = Hb;   // overlay staging, stride 176 (5632 shorts < 8960)
  for (int cc = 0; cc < 2; ++cc) {
    for (int i = tid; i < NSEQ_BLK * 160; i += 512) {
      int row = i / 160;
      int col = i - row * 160;
      int d = cc * 160 + col;
      int s = seq0 + row;
      int b = s / 6;
      float v;
      if (d < 256)      v = ctx[b * 256 + d];
      else if (d < 258) v = goals[s * 2 + (d - 256)];
      else if (d < 290) v = emb[b * 32 + (d - 258)];
      else              v = 0.f;
      As[row * 176 + col] = f2bf(v);
    }
    __syncthreads();   // also orders wNl staging (cc=0)
    for (int ks = 0; ks < 10; ++ks) {
      bf16x8 bf = ldfrag(&Wh0p[((w * 20 + cc * 10 + ks) * 64 + l) * 8]);
      bf16x8 af = ldfrag(&As[l31 * 176 + ks * 16 + grp * 8]);
      acc0 = __builtin_amdgcn_mfma_f32_32x32x16_bf16(af, bf, acc0, 0, 0, 0);
    }
    __syncthreads();
  }
  {
    float b0 = bh0[n0];
#pragma unroll
    for (int r = 0; r < 16; ++r) {
      int row = (r & 3) + 8 * (r >> 2) + 4 * grp;   // C/D layout [m74/m101]
      Hb[row * HSTR + n0] = f2bf(acc0[r] + b0);
    }
  }
  // zero xy (pos0=0) + K-pad cols 256..279
  for (int i = tid; i < NSEQ_BLK * 24; i += 512) {
    int s = i / 24, c = i - 24 * s;
    Hb[s * HSTR + 256 + c] = 0;
  }
  if (tid < 2 * NSEQ_BLK) posL[tid] = 0.f;

  float brr, bzz, bin_, bhn, wn0, wn1, wo0, wo1;
  {
    f32x4 g0 = *(const f32x4*)&gp[n0 * 12];
    f32x4 g2 = *(const f32x4*)&gp[n0 * 12 + 8];
    brr = g0[0]; bzz = g0[1]; bin_ = g0[2]; bhn = g0[3];
    wn0 = g2[0]; wn1 = g2[1]; wo0 = g2[2]; wo1 = g2[3];
  }
  const float bo0 = bout[0], bo1 = bout[1];
  __syncthreads();

  // ---------------- T recurrent steps (no weight traffic) ----------------
  for (int t = 0; t < 30; ++t) {
    // acc init = prescaled biases (phase-B adds deleted)
    f32x16 ar, az, an;
#pragma unroll
    for (int r = 0; r < 16; ++r) { ar[r] = brr; az[r] = bzz; an[r] = bhn; }

    // K-loop: ks 0..15 over h; ks=16 adds xy columns to r/z only
#pragma unroll
    for (int ks = 0; ks < 16; ++ks) {
      bf16x8 af = ldfrag(&Hb[l31 * HSTR + ks * 16 + grp * 8]);
      bf16x8 bN = ldfrag(&wNl[((w * 16 + ks) * 64 + l) * 8]);
      ar = __builtin_amdgcn_mfma_f32_32x32x16_bf16(af, wR[ks], ar, 0, 0, 0);
      az = __builtin_amdgcn_mfma_f32_32x32x16_bf16(af, wZ[ks], az, 0, 0, 0);
      an = __builtin_amdgcn_mfma_f32_32x32x16_bf16(af, bN, an, 0, 0, 0);
    }
    {
      bf16x8 af16 = ldfrag(&Hb[l31 * HSTR + 256 + grp * 8]);   // xy + zero pad
      ar = __builtin_amdgcn_mfma_f32_32x32x16_bf16(af16, wR[16], ar, 0, 0, 0);
      az = __builtin_amdgcn_mfma_f32_32x32x16_bf16(af16, wZ[16], az, 0, 0, 0);
    }
    bar_lgkm();   // barrier1: Hb reads done

    // Phase B: gates (pure exp2/rcp chains) + h update + delta partials
#pragma unroll
    for (int q2 = 0; q2 < 4; ++q2) {
      int sb = 8 * q2 + 4 * grp;
      f32x4 xyA = *(const f32x4*)&posL[sb * 2];         // pos_t of seqs sb..sb+1
      f32x4 xyB = *(const f32x4*)&posL[sb * 2 + 4];     // sb+2..sb+3
#pragma unroll
      for (int e = 0; e < 4; ++e) {
        int r = 4 * q2 + e;
        int s = sb + e;
        float x = (e == 0) ? xyA[0] : (e == 1) ? xyA[2] : (e == 2) ? xyB[0] : xyB[2];
        float y = (e == 0) ? xyA[1] : (e == 1) ? xyA[3] : (e == 2) ? xyB[1] : xyB[3];
        int ha = s * HSTR + n0;
        float h = bf2f(Hb[ha]);
        float rg = __builtin_amdgcn_rcpf(1.f + __builtin_amdgcn_exp2f(ar[r]));
        float zg = __builtin_amdgcn_rcpf(1.f + __builtin_amdgcn_exp2f(az[r]));
        float ing = fmaf(y, wn1, fmaf(x, wn0, bin_));   // n-gate xy (prescaled)
        float u = fmaf(rg, an[r], ing);
        float tt = __builtin_amdgcn_rcpf(1.f + __builtin_amdgcn_exp2f(u));
        float ng = fmaf(tt, -2.f, 1.f);                 // tanh
        float hnew = fmaf(zg, h - ng, ng);              // (1-z)*n + z*h
        Hb[ha] = f2bf(hnew);
        float dx = dpp16sum(hnew * wo0);
        float dy = dpp16sum(hnew * wo1);
        if ((l & 15) == 0) {
          int p16 = w * 2 + ((l >> 4) & 1);
          dpart[(p16 * NSEQ_BLK + s) * 2]     = dx;
          dpart[(p16 * NSEQ_BLK + s) * 2 + 1] = dy;
        }
      }
    }
    bar_lgkm();   // barrier2: h-writes + dpart visible

    // Phase C (wave 0): pos_{t+1} = pos_t + delta; store pred[t]; refresh Hb xy
    if (tid < 2 * NSEQ_BLK) {
      int s = tid >> 1, c = tid & 1;
      float d = (c == 0) ? bo0 : bo1;
#pragma unroll
      for (int q = 0; q < 16; ++q) d += dpart[(q * NSEQ_BLK + s) * 2 + c];
      float p = posL[tid] + d;
      posL[tid] = p;
      out[((seq0 + s) * 30 + t) * 2 + c] = p;
      Hb[s * HSTR + 256 + c] = f2bf(p);
    }
    bar_lgkm();   // barrier3: xy + posL visible before next K-loop / phase B
  }
}

// ---- correction: out = pred + (goal - pred_T) * (t+1)/30, in place (verified) ----
__global__ void corr_k(float* __restrict__ out, const float* __restrict__ goals) {
  __shared__ float buf[240];
  int tid = threadIdx.x;
  int s0 = blockIdx.x * 4;
  float v = 0.f;
  if (tid < 240) { v = out[s0 * 60 + tid]; buf[tid] = v; }
  __syncthreads();
  if (tid < 240) {
    int sl = tid / 60;
    int rem = tid - sl * 60;
    int t = rem >> 1, c = rem & 1;
    float pT = buf[sl * 60 + 58 + c];
    float g = goals[(s0 + sl) * 2 + c];
    out[s0 * 60 + tid] = v + (g - pT) * ((float)(t + 1) * (1.f / 30.f));
  }
}

extern "C" void kernel_launch(void* const* d_in, const int* in_sizes, int n_in,
                              void* d_out, int out_size, void* d_ws, size_t ws_size,
                              hipStream_t stream) {
  (void)in_sizes; (void)n_in; (void)out_size; (void)ws_size;
  const float* ctx  = (const float*)d_in[0];
  const float* goals= (const float*)d_in[1];
  const float* emb  = (const float*)d_in[2];
  const float* Wh0  = (const float*)d_in[3];
  const float* bh0  = (const float*)d_in[4];
  const float* Wih  = (const float*)d_in[5];
  const float* Whh  = (const float*)d_in[6];
  const float* bih  = (const float*)d_in[7];
  const float* bhh  = (const float*)d_in[8];
  const float* Wout = (const float*)d_in[9];
  const float* bout = (const float*)d_in[10];
  float* out = (float*)d_out;

  unsigned short* Whhp3 = (unsigned short*)d_ws;                       // 417792 B
  unsigned short* Wh0p  = (unsigned short*)((char*)d_ws + 417792);     // 163840 B
  float* gpo = (float*)((char*)d_ws + 417792 + 163840);                // 12288 B

  hipLaunchKernelGGL(prep_whh3_k, dim3(816), dim3(256), 0, stream, Whh, Wih, Whhp3);
  hipLaunchKernelGGL(prep_wh0_k, dim3(320), dim3(256), 0, stream, Wh0, Wh0p);
  hipLaunchKernelGGL(prep_gp_k, dim3(1), dim3(256), 0, stream, bih, bhh, Wih, Wout, gpo);
  hipLaunchKernelGGL(gru_main_k, dim3(1536), dim3(512), 0, stream,
                     ctx, goals, emb, bh0, bout, Wh0p, Whhp3, gpo, out);
  hipLaunchKernelGGL(corr_k, dim3(12288), dim3(256), 0, stream, out, goals);
}

// Round 9
// 1249.846 us; speedup vs baseline: 1.7043x; 1.0027x over previous
//
#include <hip/hip_runtime.h>

// TrajectoryDecoder r9: r6 (990us, spill-free, PASSED) + register-NEUTRAL cuts:
// (1) prescaled weights/biases (-1/ln2 r/z, +2/ln2 n; biases preloaded into
//     MFMA accs) -- sigmoid/tanh = rcp(1+exp2(fma chain)); math validated in r8.
// (2) persistent chunks: grid 512 x 3 chunks of 32 seqs; wNl staging + wR/wZ
//     preload + gp loads ONCE per block (was 3x).
// (3) phase C spread across all 8 waves (8 lanes each) -- no wave-0 tail.
// Register budget IDENTICAL to r6: 32 weight frags, 12 gp scalars, 48 acc.
// r8 lesson: +8 regs spills (~94 MB scratch, +25% time). Sentinel: WRITE~11.5MB.

typedef __attribute__((ext_vector_type(8))) short short8;
typedef __bf16 bf16x8 __attribute__((ext_vector_type(8)));
typedef float f32x16 __attribute__((ext_vector_type(16)));
typedef float f32x4 __attribute__((ext_vector_type(4)));

#define HSTR 264               // Hb stride: 528B rows; ~0 conflicts measured (r2/r3/r6)
#define NSEQ_BLK 32
#define NCHUNK 3
#define WHH3_ELEMS (24 * 16 * 64 * 8)  // 196608 = 768x256
#define WH0_ELEMS (8 * 20 * 64 * 8)    // 81920

#define SCL_RZ (-1.4426950408889634f)  // -1/ln2 : sigmoid prescale
#define SCL_N  (2.8853900817779268f)   // +2/ln2 : tanh prescale

static __device__ __forceinline__ unsigned short f2bf(float f) {
  unsigned u = __builtin_bit_cast(unsigned, f);
  u += 0x7fffu + ((u >> 16) & 1u);   // RNE
  return (unsigned short)(u >> 16);
}
static __device__ __forceinline__ float bf2f(unsigned short h) {
  unsigned u = ((unsigned)h) << 16;
  return __builtin_bit_cast(float, u);
}
static __device__ __forceinline__ bf16x8 ldfrag(const unsigned short* p) {
  return __builtin_bit_cast(bf16x8, *(const short8*)p);
}
static __device__ __forceinline__ float dpp16sum(float x) {
  x += __builtin_bit_cast(float, __builtin_amdgcn_update_dpp(0, __builtin_bit_cast(int, x), 0xB1, 0xF, 0xF, true));
  x += __builtin_bit_cast(float, __builtin_amdgcn_update_dpp(0, __builtin_bit_cast(int, x), 0x4E, 0xF, 0xF, true));
  x += __builtin_bit_cast(float, __builtin_amdgcn_update_dpp(0, __builtin_bit_cast(int, x), 0x141, 0xF, 0xF, true));
  x += __builtin_bit_cast(float, __builtin_amdgcn_update_dpp(0, __builtin_bit_cast(int, x), 0x140, 0xF, 0xF, true));
  return x;
}
// LDS-only barrier (r4/r6-verified): no vmcnt drain.
static __device__ __forceinline__ void bar_lgkm() {
  asm volatile("s_waitcnt lgkmcnt(0)\n\ts_barrier" ::: "memory");
}

// ---- prep: pack W_hh slice-major, PRESCALED: [(g*8+w)*16 + ks][lane][8] ----
__global__ void prep_whh3_k(const float* __restrict__ Whh, unsigned short* __restrict__ Whhp3) {
  int i = blockIdx.x * 256 + threadIdx.x;
  if (i >= WHH3_ELEMS) return;
  int j = i & 7;
  int lane = (i >> 3) & 63;
  int rest = i >> 9;
  int ks = rest & 15;
  int sw = rest >> 4;
  int g = sw >> 3, w = sw & 7;
  int row = g * 256 + w * 32 + (lane & 31);
  int k = ks * 16 + ((lane >> 5) << 3) + j;
  float scl = (g == 2) ? SCL_N : SCL_RZ;
  Whhp3[i] = f2bf(scl * Whh[row * 256 + k]);
}

// ---- prep: pack W_h0 (256 x 290, K padded to 320), unscaled (r6-verified) ----
__global__ void prep_wh0_k(const float* __restrict__ Wh0, unsigned short* __restrict__ Wh0p) {
  int i = blockIdx.x * 256 + threadIdx.x;
  if (i >= WH0_ELEMS) return;
  int j = i & 7;
  int lane = (i >> 3) & 63;
  int rest = i >> 9;
  int ks = rest % 20;
  int nt = rest / 20;
  int row = nt * 32 + (lane & 31);
  int k = ks * 16 + ((lane >> 5) << 3) + j;
  float v = (k < 290) ? Wh0[row * 290 + k] : 0.f;
  Wh0p[i] = f2bf(v);
}

// ---- prep: per-h-unit params, PRESCALED (12 scalars, same count as r6):
// [brr', bzz', bin', bhn', wr0', wr1', wz0', wz1', wn0', wn1', wo0, wo1] ----
__global__ void prep_gp_k(const float* __restrict__ bih, const float* __restrict__ bhh,
                          const float* __restrict__ Wih, const float* __restrict__ Wout,
                          float* __restrict__ gpo) {
  int n = threadIdx.x;
  gpo[n * 12 + 0]  = SCL_RZ * (bih[n] + bhh[n]);
  gpo[n * 12 + 1]  = SCL_RZ * (bih[n + 256] + bhh[n + 256]);
  gpo[n * 12 + 2]  = SCL_N * bih[n + 512];
  gpo[n * 12 + 3]  = SCL_N * bhh[n + 512];
  gpo[n * 12 + 4]  = SCL_RZ * Wih[n * 2 + 0];
  gpo[n * 12 + 5]  = SCL_RZ * Wih[n * 2 + 1];
  gpo[n * 12 + 6]  = SCL_RZ * Wih[(n + 256) * 2 + 0];
  gpo[n * 12 + 7]  = SCL_RZ * Wih[(n + 256) * 2 + 1];
  gpo[n * 12 + 8]  = SCL_N * Wih[(n + 512) * 2 + 0];
  gpo[n * 12 + 9]  = SCL_N * Wih[(n + 512) * 2 + 1];
  gpo[n * 12 + 10] = Wout[n];
  gpo[n * 12 + 11] = Wout[256 + n];
}

// ---------------- main fused GRU (persistent over 3 chunks) ----------------
__global__ __launch_bounds__(512, 2) void gru_main_k(
    const float* __restrict__ ctx, const float* __restrict__ goals,
    const float* __restrict__ emb, const float* __restrict__ bh0,
    const float* __restrict__ bout,
    const unsigned short* __restrict__ Wh0p,
    const unsigned short* __restrict__ Whhp3,
    const float* __restrict__ gp,
    float* __restrict__ out) {
  __shared__ __align__(16) unsigned short wNl[8 * 16 * 64 * 8];  // 131072 B
  __shared__ __align__(16) unsigned short Hb[NSEQ_BLK * HSTR];   // 16896 B
  __shared__ __align__(16) float dpart[16 * NSEQ_BLK * 2];       // 4096 B
  __shared__ __align__(16) float posL[NSEQ_BLK * 2];             // 256 B
  // total 152320 B; 1 block/CU, 8 waves (2/SIMD)

  const int tid = threadIdx.x;
  const int w = tid >> 6;
  const int l = tid & 63;
  const int l31 = l & 31;
  const int grp = l >> 5;
  const int n0 = w * 32 + l31;

  // ---- once per block: stage wN into LDS; preload wR/wZ; gp scalars ----
  {
    const short8* wsrc = (const short8*)(Whhp3 + 131072);
    short8* wdst = (short8*)wNl;
    for (int i = tid; i < 8192; i += 512) wdst[i] = wsrc[i];
  }
  bf16x8 wR[16], wZ[16];
#pragma unroll
  for (int ks = 0; ks < 16; ++ks) {
    wR[ks] = ldfrag(&Whhp3[(((0 * 8 + w) * 16 + ks) * 64 + l) * 8]);
    wZ[ks] = ldfrag(&Whhp3[(((1 * 8 + w) * 16 + ks) * 64 + l) * 8]);
  }
  float brr, bzz, bin_, bhn, wr0, wr1, wz0, wz1, wn0, wn1, wo0, wo1;
  {
    f32x4 g0 = *(const f32x4*)&gp[n0 * 12];
    f32x4 g1 = *(const f32x4*)&gp[n0 * 12 + 4];
    f32x4 g2 = *(const f32x4*)&gp[n0 * 12 + 8];
    brr = g0[0]; bzz = g0[1]; bin_ = g0[2]; bhn = g0[3];
    wr0 = g1[0]; wr1 = g1[1]; wz0 = g1[2]; wz1 = g1[3];
    wn0 = g2[0]; wn1 = g2[1]; wo0 = g2[2]; wo1 = g2[3];
  }
  const float bo0 = bout[0], bo1 = bout[1];
  const float b0 = bh0[n0];

  for (int chunk = 0; chunk < NCHUNK; ++chunk) {
    const int seq0 = (blockIdx.x * NCHUNK + chunk) * NSEQ_BLK;
    __syncthreads();   // previous chunk fully done (Hb/posL reuse); wNl staged (chunk 0)

    // ---------------- Phase 0: h0 = init_in @ W_h0^T + b_h0 ----------------
    f32x16 acc0 = f32x16{};
    unsigned short* As = Hb;   // overlay staging, stride 176
    for (int cc = 0; cc < 2; ++cc) {
      for (int i = tid; i < NSEQ_BLK * 160; i += 512) {
        int row = i / 160;
        int col = i - row * 160;
        int d = cc * 160 + col;
        int s = seq0 + row;
        int b = s / 6;
        float v;
        if (d < 256)      v = ctx[b * 256 + d];
        else if (d < 258) v = goals[s * 2 + (d - 256)];
        else if (d < 290) v = emb[b * 32 + (d - 258)];
        else              v = 0.f;
        As[row * 176 + col] = f2bf(v);
      }
      __syncthreads();
      for (int ks = 0; ks < 10; ++ks) {
        bf16x8 bf = ldfrag(&Wh0p[((w * 20 + cc * 10 + ks) * 64 + l) * 8]);
        bf16x8 af = ldfrag(&As[l31 * 176 + ks * 16 + grp * 8]);
        acc0 = __builtin_amdgcn_mfma_f32_32x32x16_bf16(af, bf, acc0, 0, 0, 0);
      }
      __syncthreads();
    }
#pragma unroll
    for (int r = 0; r < 16; ++r) {
      int row = (r & 3) + 8 * (r >> 2) + 4 * grp;   // C/D layout [m74/m101]
      Hb[row * HSTR + n0] = f2bf(acc0[r] + b0);
    }
    if (tid < 2 * NSEQ_BLK) posL[tid] = 0.f;
    __syncthreads();

    // ---------------- T recurrent steps ----------------
    for (int t = 0; t < 30; ++t) {
      // acc init = prescaled biases
      f32x16 ar, az, an;
#pragma unroll
      for (int r = 0; r < 16; ++r) { ar[r] = brr; az[r] = bzz; an[r] = bhn; }

      // K-loop: A from Hb, wR/wZ regs, wN LDS
#pragma unroll
      for (int ks = 0; ks < 16; ++ks) {
        bf16x8 af = ldfrag(&Hb[l31 * HSTR + ks * 16 + grp * 8]);
        bf16x8 bN = ldfrag(&wNl[((w * 16 + ks) * 64 + l) * 8]);
        ar = __builtin_amdgcn_mfma_f32_32x32x16_bf16(af, wR[ks], ar, 0, 0, 0);
        az = __builtin_amdgcn_mfma_f32_32x32x16_bf16(af, wZ[ks], az, 0, 0, 0);
        an = __builtin_amdgcn_mfma_f32_32x32x16_bf16(af, bN, an, 0, 0, 0);
      }
      bar_lgkm();   // barrier1: Hb reads done; posL(t-1) final

      // Phase B: gates (pure fma+exp2+rcp) + h update + delta partials
#pragma unroll
      for (int q2 = 0; q2 < 4; ++q2) {
        int sb = 8 * q2 + 4 * grp;
        f32x4 xyA = *(const f32x4*)&posL[sb * 2];
        f32x4 xyB = *(const f32x4*)&posL[sb * 2 + 4];
#pragma unroll
        for (int e = 0; e < 4; ++e) {
          int r = 4 * q2 + e;
          int s = sb + e;
          float x = (e == 0) ? xyA[0] : (e == 1) ? xyA[2] : (e == 2) ? xyB[0] : xyB[2];
          float y = (e == 0) ? xyA[1] : (e == 1) ? xyA[3] : (e == 2) ? xyB[1] : xyB[3];
          int ha = s * HSTR + n0;
          float h = bf2f(Hb[ha]);
          float vr = fmaf(y, wr1, fmaf(x, wr0, ar[r]));
          float rg = __builtin_amdgcn_rcpf(1.f + __builtin_amdgcn_exp2f(vr));
          float vz = fmaf(y, wz1, fmaf(x, wz0, az[r]));
          float zg = __builtin_amdgcn_rcpf(1.f + __builtin_amdgcn_exp2f(vz));
          float ing = fmaf(y, wn1, fmaf(x, wn0, bin_));
          float u = fmaf(rg, an[r], ing);
          float tt = __builtin_amdgcn_rcpf(1.f + __builtin_amdgcn_exp2f(u));
          float ng = fmaf(tt, -2.f, 1.f);               // tanh
          float hnew = fmaf(zg, h - ng, ng);            // (1-z)*n + z*h
          Hb[ha] = f2bf(hnew);
          float dx = dpp16sum(hnew * wo0);
          float dy = dpp16sum(hnew * wo1);
          if ((l & 15) == 0) {
            int p16 = w * 2 + ((l >> 4) & 1);
            dpart[(p16 * NSEQ_BLK + s) * 2]     = dx;
            dpart[(p16 * NSEQ_BLK + s) * 2 + 1] = dy;
          }
        }
      }
      bar_lgkm();   // barrier2: h-writes + dpart visible

      // Phase C (spread: 8 lanes of EVERY wave): pos update + pred store
      if (l < 8) {
        int i = w * 8 + l;       // 0..63
        int s = i >> 1, c = i & 1;
        float d = (c == 0) ? bo0 : bo1;
#pragma unroll
        for (int q = 0; q < 16; ++q) d += dpart[(q * NSEQ_BLK + s) * 2 + c];
        float p = posL[i] + d;
        posL[i] = p;
        out[((seq0 + s) * 30 + t) * 2 + c] = p;
      }
    }
  }
}

// ---- correction: out = pred + (goal - pred_T) * (t+1)/30, in place (verified) ----
__global__ void corr_k(float* __restrict__ out, const float* __restrict__ goals) {
  __shared__ float buf[240];
  int tid = threadIdx.x;
  int s0 = blockIdx.x * 4;
  float v = 0.f;
  if (tid < 240) { v = out[s0 * 60 + tid]; buf[tid] = v; }
  __syncthreads();
  if (tid < 240) {
    int sl = tid / 60;
    int rem = tid - sl * 60;
    int t = rem >> 1, c = rem & 1;
    float pT = buf[sl * 60 + 58 + c];
    float g = goals[(s0 + sl) * 2 + c];
    out[s0 * 60 + tid] = v + (g - pT) * ((float)(t + 1) * (1.f / 30.f));
  }
}

extern "C" void kernel_launch(void* const* d_in, const int* in_sizes, int n_in,
                              void* d_out, int out_size, void* d_ws, size_t ws_size,
                              hipStream_t stream) {
  (void)in_sizes; (void)n_in; (void)out_size; (void)ws_size;
  const float* ctx  = (const float*)d_in[0];
  const float* goals= (const float*)d_in[1];
  const float* emb  = (const float*)d_in[2];
  const float* Wh0  = (const float*)d_in[3];
  const float* bh0  = (const float*)d_in[4];
  const float* Wih  = (const float*)d_in[5];
  const float* Whh  = (const float*)d_in[6];
  const float* bih  = (const float*)d_in[7];
  const float* bhh  = (const float*)d_in[8];
  const float* Wout = (const float*)d_in[9];
  const float* bout = (const float*)d_in[10];
  float* out = (float*)d_out;

  unsigned short* Whhp3 = (unsigned short*)d_ws;                       // 393216 B
  unsigned short* Wh0p  = (unsigned short*)((char*)d_ws + 393216);     // 163840 B
  float* gpo = (float*)((char*)d_ws + 393216 + 163840);                // 12288 B

  hipLaunchKernelGGL(prep_whh3_k, dim3(768), dim3(256), 0, stream, Whh, Whhp3);
  hipLaunchKernelGGL(prep_wh0_k, dim3(320), dim3(256), 0, stream, Wh0, Wh0p);
  hipLaunchKernelGGL(prep_gp_k, dim3(1), dim3(256), 0, stream, bih, bhh, Wih, Wout, gpo);
  hipLaunchKernelGGL(gru_main_k, dim3(512), dim3(512), 0, stream,
                     ctx, goals, emb, bh0, bout, Wh0p, Whhp3, gpo, out);
  hipLaunchKernelGGL(corr_k, dim3(12288), dim3(256), 0, stream, out, goals);
}

// Round 10
// 1246.748 us; speedup vs baseline: 1.7085x; 1.0025x over previous
//
#include <hip/hip_runtime.h>

// TrajectoryDecoder r10: exact r6 skeleton (990us, spill-free, PASSED) with
// ONLY register-flat deltas: (1) prescaled weights/biases (-1/ln2 r/z, +2/ln2 n,
// biases preloaded into MFMA accs; math validated r8/r9), (2) phase C spread
// across all 8 waves. NO persistent-chunk loop (r9 lesson: it spills ~34 regs
// of wR/wZ around each phase 0). Grid 1536, NSEQ=32, 2 lgkm barriers.
// Spill sentinels: WRITE~11.5MB, VGPR<=124.

typedef __attribute__((ext_vector_type(8))) short short8;
typedef __bf16 bf16x8 __attribute__((ext_vector_type(8)));
typedef float f32x16 __attribute__((ext_vector_type(16)));
typedef float f32x4 __attribute__((ext_vector_type(4)));

#define HSTR 264               // Hb stride: 528B rows; ~0 conflicts measured (r2/r3/r6)
#define NSEQ_BLK 32
#define WHH3_ELEMS (24 * 16 * 64 * 8)  // 196608 = 768x256
#define WH0_ELEMS (8 * 20 * 64 * 8)    // 81920

#define SCL_RZ (-1.4426950408889634f)  // -1/ln2 : sigmoid prescale
#define SCL_N  (2.8853900817779268f)   // +2/ln2 : tanh prescale

static __device__ __forceinline__ unsigned short f2bf(float f) {
  unsigned u = __builtin_bit_cast(unsigned, f);
  u += 0x7fffu + ((u >> 16) & 1u);   // RNE
  return (unsigned short)(u >> 16);
}
static __device__ __forceinline__ float bf2f(unsigned short h) {
  unsigned u = ((unsigned)h) << 16;
  return __builtin_bit_cast(float, u);
}
static __device__ __forceinline__ bf16x8 ldfrag(const unsigned short* p) {
  return __builtin_bit_cast(bf16x8, *(const short8*)p);
}
static __device__ __forceinline__ float dpp16sum(float x) {
  x += __builtin_bit_cast(float, __builtin_amdgcn_update_dpp(0, __builtin_bit_cast(int, x), 0xB1, 0xF, 0xF, true));
  x += __builtin_bit_cast(float, __builtin_amdgcn_update_dpp(0, __builtin_bit_cast(int, x), 0x4E, 0xF, 0xF, true));
  x += __builtin_bit_cast(float, __builtin_amdgcn_update_dpp(0, __builtin_bit_cast(int, x), 0x141, 0xF, 0xF, true));
  x += __builtin_bit_cast(float, __builtin_amdgcn_update_dpp(0, __builtin_bit_cast(int, x), 0x140, 0xF, 0xF, true));
  return x;
}
// LDS-only barrier (r4/r6-verified): no vmcnt drain.
static __device__ __forceinline__ void bar_lgkm() {
  asm volatile("s_waitcnt lgkmcnt(0)\n\ts_barrier" ::: "memory");
}

// ---- prep: pack W_hh slice-major, PRESCALED: [(g*8+w)*16 + ks][lane][8] ----
__global__ void prep_whh3_k(const float* __restrict__ Whh, unsigned short* __restrict__ Whhp3) {
  int i = blockIdx.x * 256 + threadIdx.x;
  if (i >= WHH3_ELEMS) return;
  int j = i & 7;
  int lane = (i >> 3) & 63;
  int rest = i >> 9;
  int ks = rest & 15;
  int sw = rest >> 4;
  int g = sw >> 3, w = sw & 7;
  int row = g * 256 + w * 32 + (lane & 31);
  int k = ks * 16 + ((lane >> 5) << 3) + j;
  float scl = (g == 2) ? SCL_N : SCL_RZ;
  Whhp3[i] = f2bf(scl * Whh[row * 256 + k]);
}

// ---- prep: pack W_h0 (256 x 290, K padded to 320), unscaled (r6-verified) ----
__global__ void prep_wh0_k(const float* __restrict__ Wh0, unsigned short* __restrict__ Wh0p) {
  int i = blockIdx.x * 256 + threadIdx.x;
  if (i >= WH0_ELEMS) return;
  int j = i & 7;
  int lane = (i >> 3) & 63;
  int rest = i >> 9;
  int ks = rest % 20;
  int nt = rest / 20;
  int row = nt * 32 + (lane & 31);
  int k = ks * 16 + ((lane >> 5) << 3) + j;
  float v = (k < 290) ? Wh0[row * 290 + k] : 0.f;
  Wh0p[i] = f2bf(v);
}

// ---- prep: per-h-unit params, PRESCALED (12 scalars, same count as r6) ----
__global__ void prep_gp_k(const float* __restrict__ bih, const float* __restrict__ bhh,
                          const float* __restrict__ Wih, const float* __restrict__ Wout,
                          float* __restrict__ gpo) {
  int n = threadIdx.x;
  gpo[n * 12 + 0]  = SCL_RZ * (bih[n] + bhh[n]);
  gpo[n * 12 + 1]  = SCL_RZ * (bih[n + 256] + bhh[n + 256]);
  gpo[n * 12 + 2]  = SCL_N * bih[n + 512];
  gpo[n * 12 + 3]  = SCL_N * bhh[n + 512];
  gpo[n * 12 + 4]  = SCL_RZ * Wih[n * 2 + 0];
  gpo[n * 12 + 5]  = SCL_RZ * Wih[n * 2 + 1];
  gpo[n * 12 + 6]  = SCL_RZ * Wih[(n + 256) * 2 + 0];
  gpo[n * 12 + 7]  = SCL_RZ * Wih[(n + 256) * 2 + 1];
  gpo[n * 12 + 8]  = SCL_N * Wih[(n + 512) * 2 + 0];
  gpo[n * 12 + 9]  = SCL_N * Wih[(n + 512) * 2 + 1];
  gpo[n * 12 + 10] = Wout[n];
  gpo[n * 12 + 11] = Wout[256 + n];
}

// ---------------- main fused GRU ----------------
__global__ __launch_bounds__(512, 2) void gru_main_k(
    const float* __restrict__ ctx, const float* __restrict__ goals,
    const float* __restrict__ emb, const float* __restrict__ bh0,
    const float* __restrict__ bout,
    const unsigned short* __restrict__ Wh0p,
    const unsigned short* __restrict__ Whhp3,
    const float* __restrict__ gp,
    float* __restrict__ out) {
  __shared__ __align__(16) unsigned short wNl[8 * 16 * 64 * 8];  // 131072 B
  __shared__ __align__(16) unsigned short Hb[NSEQ_BLK * HSTR];   // 16896 B
  __shared__ __align__(16) float dpart[16 * NSEQ_BLK * 2];       // 4096 B
  __shared__ __align__(16) float posL[NSEQ_BLK * 2];             // 256 B
  // total 152320 B; 1 block/CU, 8 waves (2/SIMD)

  const int tid = threadIdx.x;
  const int w = tid >> 6;
  const int l = tid & 63;
  const int l31 = l & 31;
  const int grp = l >> 5;
  const int seq0 = blockIdx.x * NSEQ_BLK;
  const int n0 = w * 32 + l31;

  // ---- stage wN (g=2 region, 128 KB) into LDS, block-cooperative ----
  {
    const short8* wsrc = (const short8*)(Whhp3 + 131072);
    short8* wdst = (short8*)wNl;
    for (int i = tid; i < 8192; i += 512) wdst[i] = wsrc[i];
  }
  // ---- preload wR, wZ into registers (128 regs, held 30 steps) ----
  bf16x8 wR[16], wZ[16];
#pragma unroll
  for (int ks = 0; ks < 16; ++ks) {
    wR[ks] = ldfrag(&Whhp3[(((0 * 8 + w) * 16 + ks) * 64 + l) * 8]);
    wZ[ks] = ldfrag(&Whhp3[(((1 * 8 + w) * 16 + ks) * 64 + l) * 8]);
  }

  // ---------------- Phase 0: h0 = init_in @ W_h0^T + b_h0 ----------------
  f32x16 acc0 = f32x16{};
  unsigned short* As = Hb;   // overlay staging, stride 176
  for (int cc = 0; cc < 2; ++cc) {
    for (int i = tid; i < NSEQ_BLK * 160; i += 512) {
      int row = i / 160;
      int col = i - row * 160;
      int d = cc * 160 + col;
      int s = seq0 + row;
      int b = s / 6;
      float v;
      if (d < 256)      v = ctx[b * 256 + d];
      else if (d < 258) v = goals[s * 2 + (d - 256)];
      else if (d < 290) v = emb[b * 32 + (d - 258)];
      else              v = 0.f;
      As[row * 176 + col] = f2bf(v);
    }
    __syncthreads();   // also orders wNl staging (cc=0)
    for (int ks = 0; ks < 10; ++ks) {
      bf16x8 bf = ldfrag(&Wh0p[((w * 20 + cc * 10 + ks) * 64 + l) * 8]);
      bf16x8 af = ldfrag(&As[l31 * 176 + ks * 16 + grp * 8]);
      acc0 = __builtin_amdgcn_mfma_f32_32x32x16_bf16(af, bf, acc0, 0, 0, 0);
    }
    __syncthreads();
  }
  {
    float b0 = bh0[n0];
#pragma unroll
    for (int r = 0; r < 16; ++r) {
      int row = (r & 3) + 8 * (r >> 2) + 4 * grp;   // C/D layout [m74/m101]
      Hb[row * HSTR + n0] = f2bf(acc0[r] + b0);
    }
  }
  if (tid < 2 * NSEQ_BLK) posL[tid] = 0.f;

  float brr, bzz, bin_, bhn, wr0, wr1, wz0, wz1, wn0, wn1, wo0, wo1;
  {
    f32x4 g0 = *(const f32x4*)&gp[n0 * 12];
    f32x4 g1 = *(const f32x4*)&gp[n0 * 12 + 4];
    f32x4 g2 = *(const f32x4*)&gp[n0 * 12 + 8];
    brr = g0[0]; bzz = g0[1]; bin_ = g0[2]; bhn = g0[3];
    wr0 = g1[0]; wr1 = g1[1]; wz0 = g1[2]; wz1 = g1[3];
    wn0 = g2[0]; wn1 = g2[1]; wo0 = g2[2]; wo1 = g2[3];
  }
  const float bo0 = bout[0], bo1 = bout[1];
  __syncthreads();

  // ---------------- T recurrent steps (no weight traffic) ----------------
  for (int t = 0; t < 30; ++t) {
    // acc init = prescaled biases (phase-B bias adds deleted)
    f32x16 ar, az, an;
#pragma unroll
    for (int r = 0; r < 16; ++r) { ar[r] = brr; az[r] = bzz; an[r] = bhn; }

    // K-loop: A from Hb (LDS), wR/wZ from regs, wN from LDS
#pragma unroll
    for (int ks = 0; ks < 16; ++ks) {
      bf16x8 af = ldfrag(&Hb[l31 * HSTR + ks * 16 + grp * 8]);
      bf16x8 bN = ldfrag(&wNl[((w * 16 + ks) * 64 + l) * 8]);
      ar = __builtin_amdgcn_mfma_f32_32x32x16_bf16(af, wR[ks], ar, 0, 0, 0);
      az = __builtin_amdgcn_mfma_f32_32x32x16_bf16(af, wZ[ks], az, 0, 0, 0);
      an = __builtin_amdgcn_mfma_f32_32x32x16_bf16(af, bN, an, 0, 0, 0);
    }
    bar_lgkm();   // barrier1: Hb reads done; posL(t-1) final

    // Phase B: gates (pure fma+exp2+rcp) + h update + delta partials
#pragma unroll
    for (int q2 = 0; q2 < 4; ++q2) {
      int sb = 8 * q2 + 4 * grp;
      f32x4 xyA = *(const f32x4*)&posL[sb * 2];
      f32x4 xyB = *(const f32x4*)&posL[sb * 2 + 4];
#pragma unroll
      for (int e = 0; e < 4; ++e) {
        int r = 4 * q2 + e;
        int s = sb + e;
        float x = (e == 0) ? xyA[0] : (e == 1) ? xyA[2] : (e == 2) ? xyB[0] : xyB[2];
        float y = (e == 0) ? xyA[1] : (e == 1) ? xyA[3] : (e == 2) ? xyB[1] : xyB[3];
        int ha = s * HSTR + n0;
        float h = bf2f(Hb[ha]);
        float vr = fmaf(y, wr1, fmaf(x, wr0, ar[r]));
        float rg = __builtin_amdgcn_rcpf(1.f + __builtin_amdgcn_exp2f(vr));
        float vz = fmaf(y, wz1, fmaf(x, wz0, az[r]));
        float zg = __builtin_amdgcn_rcpf(1.f + __builtin_amdgcn_exp2f(vz));
        float ing = fmaf(y, wn1, fmaf(x, wn0, bin_));
        float u = fmaf(rg, an[r], ing);
        float tt = __builtin_amdgcn_rcpf(1.f + __builtin_amdgcn_exp2f(u));
        float ng = fmaf(tt, -2.f, 1.f);               // tanh
        float hnew = fmaf(zg, h - ng, ng);            // (1-z)*n + z*h
        Hb[ha] = f2bf(hnew);
        float dx = dpp16sum(hnew * wo0);
        float dy = dpp16sum(hnew * wo1);
        if ((l & 15) == 0) {
          int p16 = w * 2 + ((l >> 4) & 1);
          dpart[(p16 * NSEQ_BLK + s) * 2]     = dx;
          dpart[(p16 * NSEQ_BLK + s) * 2 + 1] = dy;
        }
      }
    }
    bar_lgkm();   // barrier2: h-writes + dpart visible

    // Phase C (spread: 8 lanes of EVERY wave): pos update + pred store
    if (l < 8) {
      int i = w * 8 + l;       // 0..63
      int s = i >> 1, c = i & 1;
      float d = (c == 0) ? bo0 : bo1;
#pragma unroll
      for (int q = 0; q < 16; ++q) d += dpart[(q * NSEQ_BLK + s) * 2 + c];
      float p = posL[i] + d;
      posL[i] = p;
      out[((seq0 + s) * 30 + t) * 2 + c] = p;
    }
  }
}

// ---- correction: out = pred + (goal - pred_T) * (t+1)/30, in place (verified) ----
__global__ void corr_k(float* __restrict__ out, const float* __restrict__ goals) {
  __shared__ float buf[240];
  int tid = threadIdx.x;
  int s0 = blockIdx.x * 4;
  float v = 0.f;
  if (tid < 240) { v = out[s0 * 60 + tid]; buf[tid] = v; }
  __syncthreads();
  if (tid < 240) {
    int sl = tid / 60;
    int rem = tid - sl * 60;
    int t = rem >> 1, c = rem & 1;
    float pT = buf[sl * 60 + 58 + c];
    float g = goals[(s0 + sl) * 2 + c];
    out[s0 * 60 + tid] = v + (g - pT) * ((float)(t + 1) * (1.f / 30.f));
  }
}

extern "C" void kernel_launch(void* const* d_in, const int* in_sizes, int n_in,
                              void* d_out, int out_size, void* d_ws, size_t ws_size,
                              hipStream_t stream) {
  (void)in_sizes; (void)n_in; (void)out_size; (void)ws_size;
  const float* ctx  = (const float*)d_in[0];
  const float* goals= (const float*)d_in[1];
  const float* emb  = (const float*)d_in[2];
  const float* Wh0  = (const float*)d_in[3];
  const float* bh0  = (const float*)d_in[4];
  const float* Wih  = (const float*)d_in[5];
  const float* Whh  = (const float*)d_in[6];
  const float* bih  = (const float*)d_in[7];
  const float* bhh  = (const float*)d_in[8];
  const float* Wout = (const float*)d_in[9];
  const float* bout = (const float*)d_in[10];
  float* out = (float*)d_out;

  unsigned short* Whhp3 = (unsigned short*)d_ws;                       // 393216 B
  unsigned short* Wh0p  = (unsigned short*)((char*)d_ws + 393216);     // 163840 B
  float* gpo = (float*)((char*)d_ws + 393216 + 163840);                // 12288 B

  hipLaunchKernelGGL(prep_whh3_k, dim3(768), dim3(256), 0, stream, Whh, Whhp3);
  hipLaunchKernelGGL(prep_wh0_k, dim3(320), dim3(256), 0, stream, Wh0, Wh0p);
  hipLaunchKernelGGL(prep_gp_k, dim3(1), dim3(256), 0, stream, bih, bhh, Wih, Wout, gpo);
  hipLaunchKernelGGL(gru_main_k, dim3(1536), dim3(512), 0, stream,
                     ctx, goals, emb, bh0, bout, Wh0p, Whhp3, gpo, out);
  hipLaunchKernelGGL(corr_k, dim3(12288), dim3(256), 0, stream, out, goals);
}

// Round 11
// 1028.165 us; speedup vs baseline: 2.0717x; 1.2126x over previous
//
#include <hip/hip_runtime.h>

// TrajectoryDecoder r11: 16x16x32 MFMA restructure for 4 waves/SIMD.
// Block = 1024 thr (16 waves), each wave owns ONE 16-unit N-tile (nt = w).
// NSEQ=32 (2 M-tiles of 16). Register budget: wR/wZ 64 + acc 24 + gp 12 +
// temps ~25 = ~125 <= 128 cap at launch_bounds(1024,4). wN in LDS (128 KB).
// Weights loaded AFTER phase 0 (r9: no liveness overlap). Prescaled gates
// (r8-validated), biases added in phase B (r10: no acc-init). Grid 1536,
// 2 lgkm barriers/step (r6 schedule). A-frag reused 6x per read.
// Spill sentinels: WRITE ~11.5 MB, VGPR <= 128.

typedef __attribute__((ext_vector_type(8))) short short8;
typedef __bf16 bf16x8 __attribute__((ext_vector_type(8)));
typedef float f32x4 __attribute__((ext_vector_type(4)));

#define HSTR 264               // Hb row stride in t-loop (shorts)
#define ASTR 328               // staging stride in phase 0 (shorts)
#define WHH_E (3 * 16 * 8 * 512)   // 196608
#define WH0_E (16 * 10 * 512)      // 81920

#define SCL_RZ (-1.4426950408889634f)  // -1/ln2 : sigmoid prescale
#define SCL_N  (2.8853900817779268f)   // +2/ln2 : tanh prescale

static __device__ __forceinline__ unsigned short f2bf(float f) {
  unsigned u = __builtin_bit_cast(unsigned, f);
  u += 0x7fffu + ((u >> 16) & 1u);   // RNE
  return (unsigned short)(u >> 16);
}
static __device__ __forceinline__ float bf2f(unsigned short h) {
  unsigned u = ((unsigned)h) << 16;
  return __builtin_bit_cast(float, u);
}
static __device__ __forceinline__ bf16x8 ldfrag(const unsigned short* p) {
  return __builtin_bit_cast(bf16x8, *(const short8*)p);
}
static __device__ __forceinline__ float dpp16sum(float x) {
  x += __builtin_bit_cast(float, __builtin_amdgcn_update_dpp(0, __builtin_bit_cast(int, x), 0xB1, 0xF, 0xF, true));
  x += __builtin_bit_cast(float, __builtin_amdgcn_update_dpp(0, __builtin_bit_cast(int, x), 0x4E, 0xF, 0xF, true));
  x += __builtin_bit_cast(float, __builtin_amdgcn_update_dpp(0, __builtin_bit_cast(int, x), 0x141, 0xF, 0xF, true));
  x += __builtin_bit_cast(float, __builtin_amdgcn_update_dpp(0, __builtin_bit_cast(int, x), 0x140, 0xF, 0xF, true));
  return x;
}
// LDS-only barrier (r4/r6-verified): no vmcnt drain.
static __device__ __forceinline__ void bar_lgkm() {
  asm volatile("s_waitcnt lgkmcnt(0)\n\ts_barrier" ::: "memory");
}

// ---- prep: pack W_hh for 16x16x32 B-frags, PRESCALED ----
// idx = ((g*16+nt)*8+ks)*512 + lane*8 + j; row = g*256 + nt*16 + (lane&15),
// k = ks*32 + ((lane>>4)<<3) + j.
__global__ void prep_whh_k(const float* __restrict__ Whh, unsigned short* __restrict__ Whhp) {
  int i = blockIdx.x * 256 + threadIdx.x;
  if (i >= WHH_E) return;
  int j = i & 7;
  int lane = (i >> 3) & 63;
  int rest = i >> 9;             // 0..383
  int ks = rest & 7;
  int nt = (rest >> 3) & 15;
  int g = rest >> 7;
  int row = g * 256 + nt * 16 + (lane & 15);
  int k = ks * 32 + ((lane >> 4) << 3) + j;
  float scl = (g == 2) ? SCL_N : SCL_RZ;
  Whhp[i] = f2bf(scl * Whh[row * 256 + k]);
}

// ---- prep: pack W_h0 (256 x 290, K padded to 320) for 16x16x32 ----
// idx = (nt*10+ks)*512 + lane*8 + j; row = nt*16+(lane&15), k = ks*32+((lane>>4)<<3)+j
__global__ void prep_wh0_k(const float* __restrict__ Wh0, unsigned short* __restrict__ Wh0p) {
  int i = blockIdx.x * 256 + threadIdx.x;
  if (i >= WH0_E) return;
  int j = i & 7;
  int lane = (i >> 3) & 63;
  int rest = i >> 9;             // 0..159
  int ks = rest % 10;
  int nt = rest / 10;
  int row = nt * 16 + (lane & 15);
  int k = ks * 32 + ((lane >> 4) << 3) + j;
  float v = (k < 290) ? Wh0[row * 290 + k] : 0.f;
  Wh0p[i] = f2bf(v);
}

// ---- prep: per-h-unit params, PRESCALED (12 scalars) ----
__global__ void prep_gp_k(const float* __restrict__ bih, const float* __restrict__ bhh,
                          const float* __restrict__ Wih, const float* __restrict__ Wout,
                          float* __restrict__ gpo) {
  int n = threadIdx.x;
  gpo[n * 12 + 0]  = SCL_RZ * (bih[n] + bhh[n]);
  gpo[n * 12 + 1]  = SCL_RZ * (bih[n + 256] + bhh[n + 256]);
  gpo[n * 12 + 2]  = SCL_N * bih[n + 512];
  gpo[n * 12 + 3]  = SCL_N * bhh[n + 512];
  gpo[n * 12 + 4]  = SCL_RZ * Wih[n * 2 + 0];
  gpo[n * 12 + 5]  = SCL_RZ * Wih[n * 2 + 1];
  gpo[n * 12 + 6]  = SCL_RZ * Wih[(n + 256) * 2 + 0];
  gpo[n * 12 + 7]  = SCL_RZ * Wih[(n + 256) * 2 + 1];
  gpo[n * 12 + 8]  = SCL_N * Wih[(n + 512) * 2 + 0];
  gpo[n * 12 + 9]  = SCL_N * Wih[(n + 512) * 2 + 1];
  gpo[n * 12 + 10] = Wout[n];
  gpo[n * 12 + 11] = Wout[256 + n];
}

// ---------------- main fused GRU ----------------
__global__ __launch_bounds__(1024, 4) void gru_main_k(
    const float* __restrict__ ctx, const float* __restrict__ goals,
    const float* __restrict__ emb, const float* __restrict__ bh0,
    const float* __restrict__ bout,
    const unsigned short* __restrict__ Wh0p,
    const unsigned short* __restrict__ Whhp,
    const float* __restrict__ gp,
    float* __restrict__ out) {
  __shared__ __align__(16) unsigned short wNl[16 * 8 * 512];  // 131072 B (n-gate)
  __shared__ __align__(16) unsigned short Hb[32 * ASTR];      // 20992 B (staging 328 / t-loop 264)
  __shared__ __align__(16) float dpart[16 * 32 * 2];          // 4096 B
  __shared__ __align__(16) float posL[64];                    // 256 B
  // total 156416 B <= 160 KiB; 1 block/CU, 16 waves (4/SIMD)

  const int tid = threadIdx.x;
  const int w = tid >> 6;        // wave 0..15 = N-tile
  const int l = tid & 63;
  const int l15 = l & 15;
  const int q = l >> 4;          // quad 0..3
  const int seq0 = blockIdx.x * 32;
  const int n0 = w * 16 + l15;   // this lane's h-unit

  // ---- stage wN (g=2 region, 128 KB) into LDS, block-cooperative ----
  {
    const short8* wsrc = (const short8*)(Whhp + 131072);
    short8* wdst = (short8*)wNl;
    for (int i = tid; i < 8192; i += 1024) wdst[i] = wsrc[i];
  }

  // ---------------- Phase 0: h0 = init_in @ W_h0^T + b_h0 ----------------
  // staging: 32 rows x 320 cols, stride 328
  for (int i = tid; i < 32 * 320; i += 1024) {
    int row = i / 320;
    int col = i - 320 * row;
    int s = seq0 + row;
    int b = s / 6;
    float v;
    if (col < 256)      v = ctx[b * 256 + col];
    else if (col < 258) v = goals[s * 2 + (col - 256)];
    else if (col < 290) v = emb[b * 32 + (col - 258)];
    else                v = 0.f;
    Hb[row * ASTR + col] = f2bf(v);
  }
  __syncthreads();   // staging + wNl visible
  f32x4 acc00 = f32x4{}, acc01 = f32x4{};
  for (int ks = 0; ks < 10; ++ks) {
    bf16x8 bf = ldfrag(&Wh0p[((w * 10 + ks) * 64 + l) * 8]);
    bf16x8 a0 = ldfrag(&Hb[l15 * ASTR + ks * 32 + q * 8]);
    bf16x8 a1 = ldfrag(&Hb[(l15 + 16) * ASTR + ks * 32 + q * 8]);
    acc00 = __builtin_amdgcn_mfma_f32_16x16x32_bf16(a0, bf, acc00, 0, 0, 0);
    acc01 = __builtin_amdgcn_mfma_f32_16x16x32_bf16(a1, bf, acc01, 0, 0, 0);
  }
  __syncthreads();   // all As reads done before Hb (overlapping region) rewrite
  {
    float b0 = bh0[n0];
#pragma unroll
    for (int r = 0; r < 4; ++r) {
      int s0r = q * 4 + r;                     // C/D: row = q*4+reg [m89/m91]
      Hb[s0r * HSTR + n0] = f2bf(acc00[r] + b0);
      Hb[(16 + s0r) * HSTR + n0] = f2bf(acc01[r] + b0);
    }
  }
  if (tid < 64) posL[tid] = 0.f;

  // ---- weights AFTER phase 0 (no liveness overlap; r9 lesson) ----
  bf16x8 wR[8], wZ[8];
#pragma unroll
  for (int ks = 0; ks < 8; ++ks) {
    wR[ks] = ldfrag(&Whhp[(((0 * 16 + w) * 8 + ks) * 64 + l) * 8]);
    wZ[ks] = ldfrag(&Whhp[(((1 * 16 + w) * 8 + ks) * 64 + l) * 8]);
  }
  float brr, bzz, bin_, bhn, wr0, wr1, wz0, wz1, wn0, wn1, wo0, wo1;
  {
    f32x4 g0 = *(const f32x4*)&gp[n0 * 12];
    f32x4 g1 = *(const f32x4*)&gp[n0 * 12 + 4];
    f32x4 g2 = *(const f32x4*)&gp[n0 * 12 + 8];
    brr = g0[0]; bzz = g0[1]; bin_ = g0[2]; bhn = g0[3];
    wr0 = g1[0]; wr1 = g1[1]; wz0 = g1[2]; wz1 = g1[3];
    wn0 = g2[0]; wn1 = g2[1]; wo0 = g2[2]; wo1 = g2[3];
  }
  const float bo0 = bout[0], bo1 = bout[1];
  __syncthreads();

  // ---------------- T recurrent steps (no weight traffic) ----------------
  for (int t = 0; t < 30; ++t) {
    f32x4 ar0 = f32x4{}, ar1 = f32x4{}, az0 = f32x4{}, az1 = f32x4{},
          an0 = f32x4{}, an1 = f32x4{};

    // K-loop: each A-frag read feeds 3 MFMAs (r,z,n); 2 M-tiles
#pragma unroll
    for (int ks = 0; ks < 8; ++ks) {
      const int ko = ks * 32 + q * 8;
      bf16x8 a0 = ldfrag(&Hb[l15 * HSTR + ko]);
      bf16x8 a1 = ldfrag(&Hb[(l15 + 16) * HSTR + ko]);
      bf16x8 bN = ldfrag(&wNl[((w * 8 + ks) * 64 + l) * 8]);
      ar0 = __builtin_amdgcn_mfma_f32_16x16x32_bf16(a0, wR[ks], ar0, 0, 0, 0);
      ar1 = __builtin_amdgcn_mfma_f32_16x16x32_bf16(a1, wR[ks], ar1, 0, 0, 0);
      az0 = __builtin_amdgcn_mfma_f32_16x16x32_bf16(a0, wZ[ks], az0, 0, 0, 0);
      az1 = __builtin_amdgcn_mfma_f32_16x16x32_bf16(a1, wZ[ks], az1, 0, 0, 0);
      an0 = __builtin_amdgcn_mfma_f32_16x16x32_bf16(a0, bN, an0, 0, 0, 0);
      an1 = __builtin_amdgcn_mfma_f32_16x16x32_bf16(a1, bN, an1, 0, 0, 0);
    }
    bar_lgkm();   // barrier1: Hb reads done; posL(t-1) final

    // Phase B: 8 elements/lane (2 M-tiles x 4 regs)
#pragma unroll
    for (int T = 0; T < 2; ++T) {
#pragma unroll
      for (int r = 0; r < 4; ++r) {
        int s = T * 16 + q * 4 + r;
        float2 xy = *(const float2*)&posL[s * 2];   // broadcast within 16-lane group
        int ha = s * HSTR + n0;
        float h = bf2f(Hb[ha]);
        float arv = T ? ar1[r] : ar0[r];
        float azv = T ? az1[r] : az0[r];
        float anv = T ? an1[r] : an0[r];
        float vr = fmaf(xy.y, wr1, fmaf(xy.x, wr0, arv + brr));
        float rg = __builtin_amdgcn_rcpf(1.f + __builtin_amdgcn_exp2f(vr));
        float vz = fmaf(xy.y, wz1, fmaf(xy.x, wz0, azv + bzz));
        float zg = __builtin_amdgcn_rcpf(1.f + __builtin_amdgcn_exp2f(vz));
        float ing = fmaf(xy.y, wn1, fmaf(xy.x, wn0, bin_));
        float u = fmaf(rg, anv + bhn, ing);
        float tt = __builtin_amdgcn_rcpf(1.f + __builtin_amdgcn_exp2f(u));
        float ng = fmaf(tt, -2.f, 1.f);             // tanh
        float hnew = fmaf(zg, h - ng, ng);          // (1-z)*n + z*h
        Hb[ha] = f2bf(hnew);
        float dx = dpp16sum(hnew * wo0);
        float dy = dpp16sum(hnew * wo1);
        if (l15 == 0) {
          dpart[(w * 32 + s) * 2]     = dx;
          dpart[(w * 32 + s) * 2 + 1] = dy;
        }
      }
    }
    bar_lgkm();   // barrier2: h-writes + dpart visible

    // Phase C (tid<64): pos update + pred store; overlaps next K-loop
    if (tid < 64) {
      int s = tid >> 1, c = tid & 1;
      float d = (c == 0) ? bo0 : bo1;
#pragma unroll
      for (int qq = 0; qq < 16; ++qq) d += dpart[(qq * 32 + s) * 2 + c];
      float p = posL[tid] + d;
      posL[tid] = p;
      out[((seq0 + s) * 30 + t) * 2 + c] = p;
    }
  }
}

// ---- correction: out = pred + (goal - pred_T) * (t+1)/30, in place (verified) ----
__global__ void corr_k(float* __restrict__ out, const float* __restrict__ goals) {
  __shared__ float buf[240];
  int tid = threadIdx.x;
  int s0 = blockIdx.x * 4;
  float v = 0.f;
  if (tid < 240) { v = out[s0 * 60 + tid]; buf[tid] = v; }
  __syncthreads();
  if (tid < 240) {
    int sl = tid / 60;
    int rem = tid - sl * 60;
    int t = rem >> 1, c = rem & 1;
    float pT = buf[sl * 60 + 58 + c];
    float g = goals[(s0 + sl) * 2 + c];
    out[s0 * 60 + tid] = v + (g - pT) * ((float)(t + 1) * (1.f / 30.f));
  }
}

extern "C" void kernel_launch(void* const* d_in, const int* in_sizes, int n_in,
                              void* d_out, int out_size, void* d_ws, size_t ws_size,
                              hipStream_t stream) {
  (void)in_sizes; (void)n_in; (void)out_size; (void)ws_size;
  const float* ctx  = (const float*)d_in[0];
  const float* goals= (const float*)d_in[1];
  const float* emb  = (const float*)d_in[2];
  const float* Wh0  = (const float*)d_in[3];
  const float* bh0  = (const float*)d_in[4];
  const float* Wih  = (const float*)d_in[5];
  const float* Whh  = (const float*)d_in[6];
  const float* bih  = (const float*)d_in[7];
  const float* bhh  = (const float*)d_in[8];
  const float* Wout = (const float*)d_in[9];
  const float* bout = (const float*)d_in[10];
  float* out = (float*)d_out;

  unsigned short* Whhp = (unsigned short*)d_ws;                        // 393216 B
  unsigned short* Wh0p = (unsigned short*)((char*)d_ws + 393216);      // 163840 B
  float* gpo = (float*)((char*)d_ws + 393216 + 163840);                // 12288 B

  hipLaunchKernelGGL(prep_whh_k, dim3(768), dim3(256), 0, stream, Whh, Whhp);
  hipLaunchKernelGGL(prep_wh0_k, dim3(320), dim3(256), 0, stream, Wh0, Wh0p);
  hipLaunchKernelGGL(prep_gp_k, dim3(1), dim3(256), 0, stream, bih, bhh, Wih, Wout, gpo);
  hipLaunchKernelGGL(gru_main_k, dim3(1536), dim3(1024), 0, stream,
                     ctx, goals, emb, bh0, bout, Wh0p, Whhp, gpo, out);
  hipLaunchKernelGGL(corr_k, dim3(12288), dim3(256), 0, stream, out, goals);
}